// Round 1
// baseline (274.313 us; speedup 1.0000x reference)
//
#include <hip/hip_runtime.h>
#include <hip/hip_bf16.h>

#define B_  2
#define S_  512
#define H_  8
#define D_  32
#define DM_ 256
#define HD_ 256
#define NROW 4

// ---------------------------------------------------------------------------
// Kernel A: QKV projection.  grid = (B*S/NROW, 3), block = 256.
// out layout: (b, h, s, d)
// ---------------------------------------------------------------------------
__global__ __launch_bounds__(256) void qkv_kernel(
    const float* __restrict__ hid, const float* __restrict__ wq,
    const float* __restrict__ wk, const float* __restrict__ wv,
    float* __restrict__ qo, float* __restrict__ ko, float* __restrict__ vo)
{
  __shared__ float hs[NROW][DM_];
  const int r0 = blockIdx.x * NROW;                 // global row in [0, B*S)
  const float* w   = (blockIdx.y == 0) ? wq : (blockIdx.y == 1) ? wk : wv;
  float*       out = (blockIdx.y == 0) ? qo : (blockIdx.y == 1) ? ko : vo;
  const int tid = threadIdx.x;

  for (int idx = tid; idx < NROW * DM_; idx += 256)
    hs[idx >> 8][idx & 255] = hid[r0 * DM_ + idx];
  __syncthreads();

  float acc[NROW] = {0.f, 0.f, 0.f, 0.f};
  const float* wp = w + tid;                        // column m = tid
  #pragma unroll 8
  for (int c4 = 0; c4 < DM_ / 4; ++c4) {
    const float w0 = wp[(4 * c4 + 0) * HD_];
    const float w1 = wp[(4 * c4 + 1) * HD_];
    const float w2 = wp[(4 * c4 + 2) * HD_];
    const float w3 = wp[(4 * c4 + 3) * HD_];
    #pragma unroll
    for (int r = 0; r < NROW; ++r) {
      const float4 hv = reinterpret_cast<const float4*>(&hs[r][0])[c4];
      acc[r] = fmaf(hv.x, w0, acc[r]);
      acc[r] = fmaf(hv.y, w1, acc[r]);
      acc[r] = fmaf(hv.z, w2, acc[r]);
      acc[r] = fmaf(hv.w, w3, acc[r]);
    }
  }
  const int h = tid >> 5, d = tid & 31;
  #pragma unroll
  for (int r = 0; r < NROW; ++r) {
    const int g = r0 + r;
    const int b = g >> 9, s = g & (S_ - 1);
    out[((b * H_ + h) * S_ + s) * D_ + d] = acc[r];
  }
}

// ---------------------------------------------------------------------------
// Kernel B: scores + mask + softmax + attn@V.  grid = B*S (block per (b,i)),
// block = 512 (thread per column j).
// scores[b,h,i,j] = sum_d q[b,h,j,d] * k[b,h,i,d] * rpe[b,i,j,d] / sqrt(D)
// mask: j < station  OR  j == i
// ---------------------------------------------------------------------------
__global__ __launch_bounds__(512) void attn_kernel(
    const float* __restrict__ rpe, const float* __restrict__ q_ws,
    const float* __restrict__ k_ws, const float* __restrict__ v_ws,
    const int* __restrict__ station_p, float* __restrict__ o_ws)
{
  __shared__ float k_lds[H_ * D_];
  __shared__ float s_lds[H_][S_];
  __shared__ float sums[H_];
  __shared__ float part_acc[256];

  const int tid = threadIdx.x;
  const int bi  = blockIdx.x;
  const int b = bi >> 9, i = bi & (S_ - 1);
  int station = station_p[0];
  if (station > S_) station = S_;
  if (station < 0)  station = 0;

  if (tid < H_ * D_)
    k_lds[tid] = k_ws[((b * H_ + (tid >> 5)) * S_ + i) * D_ + (tid & 31)];
  __syncthreads();

  // ---- scores (thread tid == column j) ----
  const int j = tid;
  const bool allowed = (j < station) || (j == i);
  float sc[H_];
  if (allowed) {
    float4 rv[8];
    const float4* rp = reinterpret_cast<const float4*>(
        rpe + (((size_t)b * S_ + i) * S_ + j) * D_);
    #pragma unroll
    for (int t = 0; t < 8; ++t) rv[t] = rp[t];
    #pragma unroll
    for (int h = 0; h < H_; ++h) {
      const float4* qp = reinterpret_cast<const float4*>(
          q_ws + ((b * H_ + h) * S_ + j) * D_);
      const float4* kp = reinterpret_cast<const float4*>(&k_lds[h * D_]);
      float acc = 0.f;
      #pragma unroll
      for (int t = 0; t < 8; ++t) {
        const float4 qv = qp[t];
        const float4 kv = kp[t];
        acc = fmaf(qv.x * kv.x, rv[t].x, acc);
        acc = fmaf(qv.y * kv.y, rv[t].y, acc);
        acc = fmaf(qv.z * kv.z, rv[t].z, acc);
        acc = fmaf(qv.w * kv.w, rv[t].w, acc);
      }
      sc[h] = acc * 0.17677669529663687f;   // 1/sqrt(32)
    }
  } else {
    #pragma unroll
    for (int h = 0; h < H_; ++h) sc[h] = -1e30f;
  }
  #pragma unroll
  for (int h = 0; h < H_; ++h) s_lds[h][j] = sc[h];
  __syncthreads();

  // ---- softmax: wave w handles head w (8 waves of 64 lanes) ----
  {
    const int w = tid >> 6, lane = tid & 63;
    float m = -1e30f;
    #pragma unroll
    for (int jj = lane; jj < S_; jj += 64) m = fmaxf(m, s_lds[w][jj]);
    #pragma unroll
    for (int o = 32; o; o >>= 1) m = fmaxf(m, __shfl_xor(m, o, 64));
    float sum = 0.f;
    #pragma unroll
    for (int jj = lane; jj < S_; jj += 64) {
      const float p = __expf(s_lds[w][jj] - m);
      s_lds[w][jj] = p;
      sum += p;
    }
    #pragma unroll
    for (int o = 32; o; o >>= 1) sum += __shfl_xor(sum, o, 64);
    if (lane == 0) sums[w] = sum;
  }
  __syncthreads();

  // ---- out[b,h,i,d] = (1/sum_h) * sum_{allowed j} p[h][j] * v[b,h,j,d] ----
  {
    const int part = tid >> 8;          // 2-way split over j
    const int hd = tid & 255;
    const int h = hd >> 5, d = hd & 31;
    const float* vp = v_ws + ((size_t)(b * H_ + h) * S_) * D_ + d;
    float acc = 0.f;
    for (int jj = part; jj < station; jj += 2)
      acc = fmaf(s_lds[h][jj], vp[jj * D_], acc);
    if (part == 0 && i >= station)
      acc = fmaf(s_lds[h][i], vp[i * D_], acc);
    if (part == 1) part_acc[hd] = acc;
    __syncthreads();
    if (part == 0) {
      acc += part_acc[hd];
      acc *= 1.f / sums[h];
      o_ws[((b * H_ + h) * S_ + i) * D_ + d] = acc;
    }
  }
}

// ---------------------------------------------------------------------------
// Kernel C: ctx = O @ fc_w + fc_b + hidden, then LayerNorm.
// grid = B*S/NROW, block = 256 (thread per output column m).
// O is read in (b,h,i,d) layout and re-flattened to (b,i,h*D+d) via LDS.
// ---------------------------------------------------------------------------
__global__ __launch_bounds__(256) void fc_ln_kernel(
    const float* __restrict__ o_ws, const float* __restrict__ fc_w,
    const float* __restrict__ fc_b, const float* __restrict__ hid,
    const float* __restrict__ ln_w, const float* __restrict__ ln_b,
    float* __restrict__ out)
{
  __shared__ float orow[NROW][HD_];
  __shared__ float red[NROW][4];
  const int tid = threadIdx.x;
  const int r0 = blockIdx.x * NROW;

  for (int idx = tid; idx < NROW * HD_; idx += 256) {
    const int r = idx >> 8, m = idx & 255;
    const int g = r0 + r;
    const int b = g >> 9, i = g & (S_ - 1);
    orow[r][m] = o_ws[((b * H_ + (m >> 5)) * S_ + i) * D_ + (m & 31)];
  }
  __syncthreads();

  float acc[NROW] = {0.f, 0.f, 0.f, 0.f};
  const float* wp = fc_w + tid;
  #pragma unroll 8
  for (int n4 = 0; n4 < HD_ / 4; ++n4) {
    const float w0 = wp[(4 * n4 + 0) * DM_];
    const float w1 = wp[(4 * n4 + 1) * DM_];
    const float w2 = wp[(4 * n4 + 2) * DM_];
    const float w3 = wp[(4 * n4 + 3) * DM_];
    #pragma unroll
    for (int r = 0; r < NROW; ++r) {
      const float4 ov = reinterpret_cast<const float4*>(&orow[r][0])[n4];
      acc[r] = fmaf(ov.x, w0, acc[r]);
      acc[r] = fmaf(ov.y, w1, acc[r]);
      acc[r] = fmaf(ov.z, w2, acc[r]);
      acc[r] = fmaf(ov.w, w3, acc[r]);
    }
  }
  const float bias = fc_b[tid];
  #pragma unroll
  for (int r = 0; r < NROW; ++r) acc[r] += bias + hid[(r0 + r) * DM_ + tid];

  // ---- LayerNorm over DM per row ----
  const int w = tid >> 6, lane = tid & 63;
  float mu[NROW];
  #pragma unroll
  for (int r = 0; r < NROW; ++r) {
    float s = acc[r];
    #pragma unroll
    for (int o = 32; o; o >>= 1) s += __shfl_xor(s, o, 64);
    if (lane == 0) red[r][w] = s;
  }
  __syncthreads();
  #pragma unroll
  for (int r = 0; r < NROW; ++r)
    mu[r] = (red[r][0] + red[r][1] + red[r][2] + red[r][3]) * (1.f / DM_);
  __syncthreads();
  #pragma unroll
  for (int r = 0; r < NROW; ++r) {
    const float dd = acc[r] - mu[r];
    float s = dd * dd;
    #pragma unroll
    for (int o = 32; o; o >>= 1) s += __shfl_xor(s, o, 64);
    if (lane == 0) red[r][w] = s;
  }
  __syncthreads();
  const float lw = ln_w[tid], lb = ln_b[tid];
  #pragma unroll
  for (int r = 0; r < NROW; ++r) {
    const float var = (red[r][0] + red[r][1] + red[r][2] + red[r][3]) * (1.f / DM_);
    out[(r0 + r) * DM_ + tid] =
        (acc[r] - mu[r]) * rsqrtf(var + 1e-6f) * lw + lb;
  }
}

// ---------------------------------------------------------------------------
extern "C" void kernel_launch(void* const* d_in, const int* in_sizes, int n_in,
                              void* d_out, int out_size, void* d_ws, size_t ws_size,
                              hipStream_t stream) {
  const float* hid = (const float*)d_in[0];
  const float* rpe = (const float*)d_in[1];
  const float* wq  = (const float*)d_in[2];
  const float* wk  = (const float*)d_in[3];
  const float* wv  = (const float*)d_in[4];
  const float* fcw = (const float*)d_in[5];
  const float* fcb = (const float*)d_in[6];
  const float* lnw = (const float*)d_in[7];
  const float* lnb = (const float*)d_in[8];
  const int* station = (const int*)d_in[9];
  float* out = (float*)d_out;

  const size_t per = (size_t)B_ * H_ * S_ * D_;   // 262144 floats
  float* q_ws = (float*)d_ws;
  float* k_ws = q_ws + per;
  float* v_ws = k_ws + per;
  float* o_ws = v_ws + per;

  dim3 gA(B_ * S_ / NROW, 3);
  qkv_kernel<<<gA, 256, 0, stream>>>(hid, wq, wk, wv, q_ws, k_ws, v_ws);
  attn_kernel<<<B_ * S_, 512, 0, stream>>>(rpe, q_ws, k_ws, v_ws, station, o_ws);
  fc_ln_kernel<<<B_ * S_ / NROW, 256, 0, stream>>>(o_ws, fcw, fcb, hid, lnw, lnb, out);
}

// Round 2
// 208.534 us; speedup vs baseline: 1.3154x; 1.3154x over previous
//
#include <hip/hip_runtime.h>
#include <hip/hip_bf16.h>

#define B_  2
#define S_  512
#define H_  8
#define D_  32
#define DM_ 256
#define HD_ 256
#define NROW 4
#define HPB 4          // heads per attention block
#define PSTR (S_ + 4)  // padded p-row stride (516: bank offset 4 per head)

// ---------------------------------------------------------------------------
// Kernel A: QKV projection.  grid = (B*S/NROW, 3), block = 256.
// out layout: (b, h, s, d)
// ---------------------------------------------------------------------------
__global__ __launch_bounds__(256) void qkv_kernel(
    const float* __restrict__ hid, const float* __restrict__ wq,
    const float* __restrict__ wk, const float* __restrict__ wv,
    float* __restrict__ qo, float* __restrict__ ko, float* __restrict__ vo)
{
  __shared__ float hs[NROW][DM_];
  const int r0 = blockIdx.x * NROW;                 // global row in [0, B*S)
  const float* w   = (blockIdx.y == 0) ? wq : (blockIdx.y == 1) ? wk : wv;
  float*       out = (blockIdx.y == 0) ? qo : (blockIdx.y == 1) ? ko : vo;
  const int tid = threadIdx.x;

  for (int idx = tid; idx < NROW * DM_; idx += 256)
    hs[idx >> 8][idx & 255] = hid[r0 * DM_ + idx];
  __syncthreads();

  float acc[NROW] = {0.f, 0.f, 0.f, 0.f};
  const float* wp = w + tid;                        // column m = tid
  #pragma unroll 8
  for (int c4 = 0; c4 < DM_ / 4; ++c4) {
    const float w0 = wp[(4 * c4 + 0) * HD_];
    const float w1 = wp[(4 * c4 + 1) * HD_];
    const float w2 = wp[(4 * c4 + 2) * HD_];
    const float w3 = wp[(4 * c4 + 3) * HD_];
    #pragma unroll
    for (int r = 0; r < NROW; ++r) {
      const float4 hv = reinterpret_cast<const float4*>(&hs[r][0])[c4];
      acc[r] = fmaf(hv.x, w0, acc[r]);
      acc[r] = fmaf(hv.y, w1, acc[r]);
      acc[r] = fmaf(hv.z, w2, acc[r]);
      acc[r] = fmaf(hv.w, w3, acc[r]);
    }
  }
  const int h = tid >> 5, d = tid & 31;
  #pragma unroll
  for (int r = 0; r < NROW; ++r) {
    const int g = r0 + r;
    const int b = g >> 9, s = g & (S_ - 1);
    out[((b * H_ + h) * S_ + s) * D_ + d] = acc[r];
  }
}

// ---------------------------------------------------------------------------
// Kernel B: scores + mask + softmax + attn@V.
// grid = (B, S, 2): block handles (b, i, 4 heads).  block = 512.
// scores[b,h,i,j] = sum_d q[b,h,j,d] * k[b,h,i,d] * rpe[b,i,j,d] / sqrt(D)
// mask: j < station  OR  j == i
// ---------------------------------------------------------------------------
__global__ __launch_bounds__(512) void attn_kernel(
    const float* __restrict__ rpe, const float* __restrict__ q_ws,
    const float* __restrict__ k_ws, const float* __restrict__ v_ws,
    const int* __restrict__ station_p, float* __restrict__ o_ws)
{
  __shared__ float k_lds[HPB * D_];
  __shared__ float p_lds[HPB][PSTR];
  __shared__ float sums[HPB];
  __shared__ float4 red[16][32];     // [part][h*8+d4]

  const int tid = threadIdx.x;
  const int b  = blockIdx.x;
  const int i  = blockIdx.y;
  const int h0 = blockIdx.z * HPB;
  int station = station_p[0];
  if (station > S_) station = S_;
  if (station < 0)  station = 0;

  if (tid < HPB * D_)
    k_lds[tid] = k_ws[((b * H_ + h0 + (tid >> 5)) * S_ + i) * D_ + (tid & 31)];
  __syncthreads();

  // ---- scores (thread tid == column j) ----
  const int j = tid;
  const bool allowed = (j < station) || (j == i);
  float sc[HPB];
  if (allowed) {
    float4 rv[8];
    const float4* rp = reinterpret_cast<const float4*>(
        rpe + (((size_t)b * S_ + i) * S_ + j) * D_);
    #pragma unroll
    for (int t = 0; t < 8; ++t) rv[t] = rp[t];
    #pragma unroll
    for (int hh = 0; hh < HPB; ++hh) {
      const float4* qp = reinterpret_cast<const float4*>(
          q_ws + ((b * H_ + h0 + hh) * S_ + j) * D_);
      const float4* kp = reinterpret_cast<const float4*>(&k_lds[hh * D_]);
      float acc = 0.f;
      #pragma unroll
      for (int t = 0; t < 8; ++t) {
        const float4 qv = qp[t];
        const float4 kv = kp[t];
        acc = fmaf(qv.x * kv.x, rv[t].x, acc);
        acc = fmaf(qv.y * kv.y, rv[t].y, acc);
        acc = fmaf(qv.z * kv.z, rv[t].z, acc);
        acc = fmaf(qv.w * kv.w, rv[t].w, acc);
      }
      sc[hh] = acc * 0.17677669529663687f;   // 1/sqrt(32)
    }
  } else {
    #pragma unroll
    for (int hh = 0; hh < HPB; ++hh) sc[hh] = -1e30f;
  }
  #pragma unroll
  for (int hh = 0; hh < HPB; ++hh) p_lds[hh][j] = sc[hh];
  __syncthreads();

  // ---- softmax: wave w in [0,4) handles head w ----
  if (tid < HPB * 64) {
    const int w = tid >> 6, lane = tid & 63;
    float m = -1e30f;
    #pragma unroll
    for (int jj = lane; jj < S_; jj += 64) m = fmaxf(m, p_lds[w][jj]);
    #pragma unroll
    for (int o = 32; o; o >>= 1) m = fmaxf(m, __shfl_xor(m, o, 64));
    float sum = 0.f;
    #pragma unroll
    for (int jj = lane; jj < S_; jj += 64) {
      const float p = __expf(p_lds[w][jj] - m);
      p_lds[w][jj] = p;
      sum += p;
    }
    #pragma unroll
    for (int o = 32; o; o >>= 1) sum += __shfl_xor(sum, o, 64);
    if (lane == 0) sums[w] = sum;
  }
  __syncthreads();

  // ---- attn @ V: 16-way j split, float4 over d ----
  {
    const int part = tid >> 5;          // 0..15
    const int hd   = tid & 31;          // hh*8 + d4
    const int hh = hd >> 3, d4 = hd & 7;
    const float4* vp = reinterpret_cast<const float4*>(
        v_ws + ((size_t)(b * H_ + h0 + hh) * S_) * D_) + d4;   // + j*8
    float4 acc = {0.f, 0.f, 0.f, 0.f};
    #pragma unroll 4
    for (int jj = part; jj < station; jj += 16) {
      const float p = p_lds[hh][jj];
      const float4 v = vp[jj * (D_ / 4)];
      acc.x = fmaf(p, v.x, acc.x);
      acc.y = fmaf(p, v.y, acc.y);
      acc.z = fmaf(p, v.z, acc.z);
      acc.w = fmaf(p, v.w, acc.w);
    }
    if (i >= station && part == (i & 15)) {
      const float p = p_lds[hh][i];
      const float4 v = vp[i * (D_ / 4)];
      acc.x = fmaf(p, v.x, acc.x);
      acc.y = fmaf(p, v.y, acc.y);
      acc.z = fmaf(p, v.z, acc.z);
      acc.w = fmaf(p, v.w, acc.w);
    }
    red[part][hd] = acc;
  }
  __syncthreads();
  {
    const int part = tid >> 5, hd = tid & 31;
    if (part < 4) {
      float4 a = red[part][hd];
      const float4 b4 = red[part + 4][hd];
      const float4 c4 = red[part + 8][hd];
      const float4 d4v = red[part + 12][hd];
      a.x += b4.x + c4.x + d4v.x;
      a.y += b4.y + c4.y + d4v.y;
      a.z += b4.z + c4.z + d4v.z;
      a.w += b4.w + c4.w + d4v.w;
      red[part][hd] = a;
    }
  }
  __syncthreads();
  {
    const int part = tid >> 5, hd = tid & 31;
    if (part == 0) {
      const int hh = hd >> 3, d4 = hd & 7;
      float4 a = red[0][hd];
      const float4 b4 = red[1][hd];
      const float4 c4 = red[2][hd];
      const float4 d4v = red[3][hd];
      a.x += b4.x + c4.x + d4v.x;
      a.y += b4.y + c4.y + d4v.y;
      a.z += b4.z + c4.z + d4v.z;
      a.w += b4.w + c4.w + d4v.w;
      const float inv = 1.f / sums[hh];
      a.x *= inv; a.y *= inv; a.z *= inv; a.w *= inv;
      reinterpret_cast<float4*>(
          o_ws + ((b * H_ + h0 + hh) * S_ + i) * D_)[d4] = a;
    }
  }
}

// ---------------------------------------------------------------------------
// Kernel C: ctx = O @ fc_w + fc_b + hidden, then LayerNorm.
// grid = B*S/NROW, block = 256 (thread per output column m).
// ---------------------------------------------------------------------------
__global__ __launch_bounds__(256) void fc_ln_kernel(
    const float* __restrict__ o_ws, const float* __restrict__ fc_w,
    const float* __restrict__ fc_b, const float* __restrict__ hid,
    const float* __restrict__ ln_w, const float* __restrict__ ln_b,
    float* __restrict__ out)
{
  __shared__ float orow[NROW][HD_];
  __shared__ float red[NROW][4];
  const int tid = threadIdx.x;
  const int r0 = blockIdx.x * NROW;

  for (int idx = tid; idx < NROW * HD_; idx += 256) {
    const int r = idx >> 8, m = idx & 255;
    const int g = r0 + r;
    const int b = g >> 9, i = g & (S_ - 1);
    orow[r][m] = o_ws[((b * H_ + (m >> 5)) * S_ + i) * D_ + (m & 31)];
  }
  __syncthreads();

  float acc[NROW] = {0.f, 0.f, 0.f, 0.f};
  const float* wp = fc_w + tid;
  #pragma unroll 8
  for (int n4 = 0; n4 < HD_ / 4; ++n4) {
    const float w0 = wp[(4 * n4 + 0) * DM_];
    const float w1 = wp[(4 * n4 + 1) * DM_];
    const float w2 = wp[(4 * n4 + 2) * DM_];
    const float w3 = wp[(4 * n4 + 3) * DM_];
    #pragma unroll
    for (int r = 0; r < NROW; ++r) {
      const float4 ov = reinterpret_cast<const float4*>(&orow[r][0])[n4];
      acc[r] = fmaf(ov.x, w0, acc[r]);
      acc[r] = fmaf(ov.y, w1, acc[r]);
      acc[r] = fmaf(ov.z, w2, acc[r]);
      acc[r] = fmaf(ov.w, w3, acc[r]);
    }
  }
  const float bias = fc_b[tid];
  #pragma unroll
  for (int r = 0; r < NROW; ++r) acc[r] += bias + hid[(r0 + r) * DM_ + tid];

  // ---- LayerNorm over DM per row ----
  const int w = tid >> 6, lane = tid & 63;
  float mu[NROW];
  #pragma unroll
  for (int r = 0; r < NROW; ++r) {
    float s = acc[r];
    #pragma unroll
    for (int o = 32; o; o >>= 1) s += __shfl_xor(s, o, 64);
    if (lane == 0) red[r][w] = s;
  }
  __syncthreads();
  #pragma unroll
  for (int r = 0; r < NROW; ++r)
    mu[r] = (red[r][0] + red[r][1] + red[r][2] + red[r][3]) * (1.f / DM_);
  __syncthreads();
  #pragma unroll
  for (int r = 0; r < NROW; ++r) {
    const float dd = acc[r] - mu[r];
    float s = dd * dd;
    #pragma unroll
    for (int o = 32; o; o >>= 1) s += __shfl_xor(s, o, 64);
    if (lane == 0) red[r][w] = s;
  }
  __syncthreads();
  const float lw = ln_w[tid], lb = ln_b[tid];
  #pragma unroll
  for (int r = 0; r < NROW; ++r) {
    const float var = (red[r][0] + red[r][1] + red[r][2] + red[r][3]) * (1.f / DM_);
    out[(r0 + r) * DM_ + tid] =
        (acc[r] - mu[r]) * rsqrtf(var + 1e-6f) * lw + lb;
  }
}

// ---------------------------------------------------------------------------
extern "C" void kernel_launch(void* const* d_in, const int* in_sizes, int n_in,
                              void* d_out, int out_size, void* d_ws, size_t ws_size,
                              hipStream_t stream) {
  const float* hid = (const float*)d_in[0];
  const float* rpe = (const float*)d_in[1];
  const float* wq  = (const float*)d_in[2];
  const float* wk  = (const float*)d_in[3];
  const float* wv  = (const float*)d_in[4];
  const float* fcw = (const float*)d_in[5];
  const float* fcb = (const float*)d_in[6];
  const float* lnw = (const float*)d_in[7];
  const float* lnb = (const float*)d_in[8];
  const int* station = (const int*)d_in[9];
  float* out = (float*)d_out;

  const size_t per = (size_t)B_ * H_ * S_ * D_;   // 262144 floats
  float* q_ws = (float*)d_ws;
  float* k_ws = q_ws + per;
  float* v_ws = k_ws + per;
  float* o_ws = v_ws + per;

  dim3 gA(B_ * S_ / NROW, 3);
  qkv_kernel<<<gA, 256, 0, stream>>>(hid, wq, wk, wv, q_ws, k_ws, v_ws);
  dim3 gB(B_, S_, H_ / HPB);
  attn_kernel<<<gB, 512, 0, stream>>>(rpe, q_ws, k_ws, v_ws, station, o_ws);
  fc_ln_kernel<<<B_ * S_ / NROW, 256, 0, stream>>>(o_ws, fcw, fcb, hid, lnw, lnb, out);
}

// Round 3
// 181.056 us; speedup vs baseline: 1.5151x; 1.1518x over previous
//
#include <hip/hip_runtime.h>
#include <hip/hip_bf16.h>

#define B_  2
#define S_  512
#define H_  8
#define D_  32
#define DM_ 256
#define HD_ 256
#define NROW 4
#define TI  8          // i-rows per attention block
#define PSTR 520       // padded p-row stride (8-bank rotation per row)

// ---------------------------------------------------------------------------
// Kernel A: QKV projection.  grid = (B*S/NROW, 3), block = 256.
// out layout: (b, h, s, d)
// ---------------------------------------------------------------------------
__global__ __launch_bounds__(256) void qkv_kernel(
    const float* __restrict__ hid, const float* __restrict__ wq,
    const float* __restrict__ wk, const float* __restrict__ wv,
    float* __restrict__ qo, float* __restrict__ ko, float* __restrict__ vo)
{
  __shared__ float hs[NROW][DM_];
  const int r0 = blockIdx.x * NROW;                 // global row in [0, B*S)
  const float* w   = (blockIdx.y == 0) ? wq : (blockIdx.y == 1) ? wk : wv;
  float*       out = (blockIdx.y == 0) ? qo : (blockIdx.y == 1) ? ko : vo;
  const int tid = threadIdx.x;

  for (int idx = tid; idx < NROW * DM_; idx += 256)
    hs[idx >> 8][idx & 255] = hid[r0 * DM_ + idx];
  __syncthreads();

  float acc[NROW] = {0.f, 0.f, 0.f, 0.f};
  const float* wp = w + tid;                        // column m = tid
  #pragma unroll 8
  for (int c4 = 0; c4 < DM_ / 4; ++c4) {
    const float w0 = wp[(4 * c4 + 0) * HD_];
    const float w1 = wp[(4 * c4 + 1) * HD_];
    const float w2 = wp[(4 * c4 + 2) * HD_];
    const float w3 = wp[(4 * c4 + 3) * HD_];
    #pragma unroll
    for (int r = 0; r < NROW; ++r) {
      const float4 hv = reinterpret_cast<const float4*>(&hs[r][0])[c4];
      acc[r] = fmaf(hv.x, w0, acc[r]);
      acc[r] = fmaf(hv.y, w1, acc[r]);
      acc[r] = fmaf(hv.z, w2, acc[r]);
      acc[r] = fmaf(hv.w, w3, acc[r]);
    }
  }
  const int h = tid >> 5, d = tid & 31;
  #pragma unroll
  for (int r = 0; r < NROW; ++r) {
    const int g = r0 + r;
    const int b = g >> 9, s = g & (S_ - 1);
    out[((b * H_ + h) * S_ + s) * D_ + d] = acc[r];
  }
}

// ---------------------------------------------------------------------------
// Kernel B: scores + mask + softmax + attn@V, i-tiled.
// grid = (B, S/TI, H): block handles (b, 8 rows of i, 1 head).  block = 512.
// scores[b,h,i,j] = sum_d q[b,h,j,d] * k[b,h,i,d] * rpe[b,i,j,d] / sqrt(D)
// mask: j < station  OR  j == i
// q row loaded ONCE per thread (reused over 8 i); V rows shared over 8 i.
// ---------------------------------------------------------------------------
__global__ __launch_bounds__(512) void attn_kernel(
    const float* __restrict__ rpe, const float* __restrict__ q_ws,
    const float* __restrict__ k_ws, const float* __restrict__ v_ws,
    const int* __restrict__ station_p, float* __restrict__ o_ws)
{
  __shared__ float k_lds[TI * D_];
  __shared__ float p_lds[TI][PSTR];
  __shared__ float sums[TI];
  __shared__ float4 red[8][64];      // [wave/part][ii*8+d4]

  const int tid = threadIdx.x;
  const int b  = blockIdx.x;
  const int i0 = blockIdx.y * TI;
  const int h  = blockIdx.z;
  int station = station_p[0];
  if (station > S_) station = S_;
  if (station < 0)  station = 0;

  if (tid < TI * D_)
    k_lds[tid] = k_ws[((b * H_ + h) * S_ + i0 + (tid >> 5)) * D_ + (tid & 31)];
  __syncthreads();

  // ---- scores (thread tid == column j; loop over the 8 i-rows) ----
  const int j = tid;
  const bool jlt = (j < station);
  const bool intile = (j >= i0) && (j < i0 + TI);

  float4 qv[8];
  if (jlt || intile) {
    const float4* qp = reinterpret_cast<const float4*>(
        q_ws + ((b * H_ + h) * S_ + j) * D_);
    #pragma unroll
    for (int t = 0; t < 8; ++t) qv[t] = qp[t];
  }

  // software-pipelined rpe loads across the i-loop
  const float4* rbase = reinterpret_cast<const float4*>(
      rpe + (((size_t)b * S_ + i0) * S_ + j) * D_);
  const int rstride = S_ * D_ / 4;   // float4 units between consecutive i

  float4 rcur[8];
  if (jlt || (j == i0)) {
    #pragma unroll
    for (int t = 0; t < 8; ++t) rcur[t] = rbase[t];
  }
  #pragma unroll
  for (int ii = 0; ii < TI; ++ii) {
    const int i = i0 + ii;
    const bool ok = jlt || (j == i);
    float4 rnext[8];
    if (ii < TI - 1 && (jlt || (j == i + 1))) {
      const float4* rp = rbase + (ii + 1) * rstride;
      #pragma unroll
      for (int t = 0; t < 8; ++t) rnext[t] = rp[t];
    }
    float s = -1e30f;
    if (ok) {
      const float4* kp = reinterpret_cast<const float4*>(&k_lds[ii * D_]);
      float acc = 0.f;
      #pragma unroll
      for (int t = 0; t < 8; ++t) {
        const float4 kv = kp[t];
        acc = fmaf(qv[t].x * kv.x, rcur[t].x, acc);
        acc = fmaf(qv[t].y * kv.y, rcur[t].y, acc);
        acc = fmaf(qv[t].z * kv.z, rcur[t].z, acc);
        acc = fmaf(qv[t].w * kv.w, rcur[t].w, acc);
      }
      s = acc * 0.17677669529663687f;   // 1/sqrt(32)
    }
    p_lds[ii][j] = s;
    #pragma unroll
    for (int t = 0; t < 8; ++t) rcur[t] = rnext[t];
  }
  __syncthreads();

  // ---- softmax: wave w handles row i0+w ----
  {
    const int w = tid >> 6, lane = tid & 63;
    float m = -1e30f;
    #pragma unroll
    for (int jj = lane; jj < S_; jj += 64) m = fmaxf(m, p_lds[w][jj]);
    #pragma unroll
    for (int o = 32; o; o >>= 1) m = fmaxf(m, __shfl_xor(m, o, 64));
    float sum = 0.f;
    #pragma unroll
    for (int jj = lane; jj < S_; jj += 64) {
      const float p = __expf(p_lds[w][jj] - m);
      p_lds[w][jj] = p;
      sum += p;
    }
    #pragma unroll
    for (int o = 32; o; o >>= 1) sum += __shfl_xor(sum, o, 64);
    if (lane == 0) sums[w] = sum;
  }
  __syncthreads();

  // ---- attn @ V: 8-way j split (wave = part), lanes = (ii, d4) ----
  {
    const int part = tid >> 6;          // 0..7 (wave id)
    const int t    = tid & 63;
    const int ii = t >> 3, d4 = t & 7;
    const float4* vp = reinterpret_cast<const float4*>(
        v_ws + ((size_t)(b * H_ + h) * S_) * D_) + d4;   // + j*8
    float4 acc = {0.f, 0.f, 0.f, 0.f};
    #pragma unroll 4
    for (int jj = part; jj < station; jj += 8) {
      const float p = p_lds[ii][jj];
      const float4 v = vp[jj * (D_ / 4)];
      acc.x = fmaf(p, v.x, acc.x);
      acc.y = fmaf(p, v.y, acc.y);
      acc.z = fmaf(p, v.z, acc.z);
      acc.w = fmaf(p, v.w, acc.w);
    }
    const int ig = i0 + ii;
    if (ig >= station && part == (ig & 7)) {
      const float p = p_lds[ii][ig];
      const float4 v = vp[ig * (D_ / 4)];
      acc.x = fmaf(p, v.x, acc.x);
      acc.y = fmaf(p, v.y, acc.y);
      acc.z = fmaf(p, v.z, acc.z);
      acc.w = fmaf(p, v.w, acc.w);
    }
    red[part][t] = acc;
  }
  __syncthreads();
  if (tid < 64) {
    const int ii = tid >> 3, d4 = tid & 7;
    float4 a = red[0][tid];
    #pragma unroll
    for (int p = 1; p < 8; ++p) {
      const float4 r = red[p][tid];
      a.x += r.x; a.y += r.y; a.z += r.z; a.w += r.w;
    }
    const float inv = 1.f / sums[ii];
    a.x *= inv; a.y *= inv; a.z *= inv; a.w *= inv;
    reinterpret_cast<float4*>(
        o_ws + ((b * H_ + h) * S_ + i0 + ii) * D_)[d4] = a;
  }
}

// ---------------------------------------------------------------------------
// Kernel C: ctx = O @ fc_w + fc_b + hidden, then LayerNorm.
// grid = B*S/NROW, block = 256 (thread per output column m).
// ---------------------------------------------------------------------------
__global__ __launch_bounds__(256) void fc_ln_kernel(
    const float* __restrict__ o_ws, const float* __restrict__ fc_w,
    const float* __restrict__ fc_b, const float* __restrict__ hid,
    const float* __restrict__ ln_w, const float* __restrict__ ln_b,
    float* __restrict__ out)
{
  __shared__ float orow[NROW][HD_];
  __shared__ float red[NROW][4];
  const int tid = threadIdx.x;
  const int r0 = blockIdx.x * NROW;

  for (int idx = tid; idx < NROW * HD_; idx += 256) {
    const int r = idx >> 8, m = idx & 255;
    const int g = r0 + r;
    const int b = g >> 9, i = g & (S_ - 1);
    orow[r][m] = o_ws[((b * H_ + (m >> 5)) * S_ + i) * D_ + (m & 31)];
  }
  __syncthreads();

  float acc[NROW] = {0.f, 0.f, 0.f, 0.f};
  const float* wp = fc_w + tid;
  #pragma unroll 8
  for (int n4 = 0; n4 < HD_ / 4; ++n4) {
    const float w0 = wp[(4 * n4 + 0) * DM_];
    const float w1 = wp[(4 * n4 + 1) * DM_];
    const float w2 = wp[(4 * n4 + 2) * DM_];
    const float w3 = wp[(4 * n4 + 3) * DM_];
    #pragma unroll
    for (int r = 0; r < NROW; ++r) {
      const float4 ov = reinterpret_cast<const float4*>(&orow[r][0])[n4];
      acc[r] = fmaf(ov.x, w0, acc[r]);
      acc[r] = fmaf(ov.y, w1, acc[r]);
      acc[r] = fmaf(ov.z, w2, acc[r]);
      acc[r] = fmaf(ov.w, w3, acc[r]);
    }
  }
  const float bias = fc_b[tid];
  #pragma unroll
  for (int r = 0; r < NROW; ++r) acc[r] += bias + hid[(r0 + r) * DM_ + tid];

  // ---- LayerNorm over DM per row ----
  const int w = tid >> 6, lane = tid & 63;
  float mu[NROW];
  #pragma unroll
  for (int r = 0; r < NROW; ++r) {
    float s = acc[r];
    #pragma unroll
    for (int o = 32; o; o >>= 1) s += __shfl_xor(s, o, 64);
    if (lane == 0) red[r][w] = s;
  }
  __syncthreads();
  #pragma unroll
  for (int r = 0; r < NROW; ++r)
    mu[r] = (red[r][0] + red[r][1] + red[r][2] + red[r][3]) * (1.f / DM_);
  __syncthreads();
  #pragma unroll
  for (int r = 0; r < NROW; ++r) {
    const float dd = acc[r] - mu[r];
    float s = dd * dd;
    #pragma unroll
    for (int o = 32; o; o >>= 1) s += __shfl_xor(s, o, 64);
    if (lane == 0) red[r][w] = s;
  }
  __syncthreads();
  const float lw = ln_w[tid], lb = ln_b[tid];
  #pragma unroll
  for (int r = 0; r < NROW; ++r) {
    const float var = (red[r][0] + red[r][1] + red[r][2] + red[r][3]) * (1.f / DM_);
    out[(r0 + r) * DM_ + tid] =
        (acc[r] - mu[r]) * rsqrtf(var + 1e-6f) * lw + lb;
  }
}

// ---------------------------------------------------------------------------
extern "C" void kernel_launch(void* const* d_in, const int* in_sizes, int n_in,
                              void* d_out, int out_size, void* d_ws, size_t ws_size,
                              hipStream_t stream) {
  const float* hid = (const float*)d_in[0];
  const float* rpe = (const float*)d_in[1];
  const float* wq  = (const float*)d_in[2];
  const float* wk  = (const float*)d_in[3];
  const float* wv  = (const float*)d_in[4];
  const float* fcw = (const float*)d_in[5];
  const float* fcb = (const float*)d_in[6];
  const float* lnw = (const float*)d_in[7];
  const float* lnb = (const float*)d_in[8];
  const int* station = (const int*)d_in[9];
  float* out = (float*)d_out;

  const size_t per = (size_t)B_ * H_ * S_ * D_;   // 262144 floats
  float* q_ws = (float*)d_ws;
  float* k_ws = q_ws + per;
  float* v_ws = k_ws + per;
  float* o_ws = v_ws + per;

  dim3 gA(B_ * S_ / NROW, 3);
  qkv_kernel<<<gA, 256, 0, stream>>>(hid, wq, wk, wv, q_ws, k_ws, v_ws);
  dim3 gB(B_, S_ / TI, H_);
  attn_kernel<<<gB, 512, 0, stream>>>(rpe, q_ws, k_ws, v_ws, station, o_ws);
  fc_ln_kernel<<<B_ * S_ / NROW, 256, 0, stream>>>(o_ws, fcw, fcb, hid, lnw, lnb, out);
}

// Round 4
// 168.434 us; speedup vs baseline: 1.6286x; 1.0749x over previous
//
#include <hip/hip_runtime.h>
#include <hip/hip_bf16.h>

#define B_  2
#define S_  512
#define H_  8
#define D_  32
#define DM_ 256
#define HD_ 256
#define NROW 4
#define TI  8          // i-rows per attention block
#define HC  2          // heads per attention block
#define NR  (TI * HC)  // 16 p-rows per block
#define PSTR 520       // padded p-row stride (8-bank rotation per row)

// ---------------------------------------------------------------------------
// Kernel A: QKV projection.  grid = (B*S/NROW, 3), block = 256.
// out layout: (b, h, s, d)
// ---------------------------------------------------------------------------
__global__ __launch_bounds__(256) void qkv_kernel(
    const float* __restrict__ hid, const float* __restrict__ wq,
    const float* __restrict__ wk, const float* __restrict__ wv,
    float* __restrict__ qo, float* __restrict__ ko, float* __restrict__ vo)
{
  __shared__ float hs[NROW][DM_];
  const int r0 = blockIdx.x * NROW;                 // global row in [0, B*S)
  const float* w   = (blockIdx.y == 0) ? wq : (blockIdx.y == 1) ? wk : wv;
  float*       out = (blockIdx.y == 0) ? qo : (blockIdx.y == 1) ? ko : vo;
  const int tid = threadIdx.x;

  for (int idx = tid; idx < NROW * DM_; idx += 256)
    hs[idx >> 8][idx & 255] = hid[r0 * DM_ + idx];
  __syncthreads();

  float acc[NROW] = {0.f, 0.f, 0.f, 0.f};
  const float* wp = w + tid;                        // column m = tid
  #pragma unroll 8
  for (int c4 = 0; c4 < DM_ / 4; ++c4) {
    const float w0 = wp[(4 * c4 + 0) * HD_];
    const float w1 = wp[(4 * c4 + 1) * HD_];
    const float w2 = wp[(4 * c4 + 2) * HD_];
    const float w3 = wp[(4 * c4 + 3) * HD_];
    #pragma unroll
    for (int r = 0; r < NROW; ++r) {
      const float4 hv = reinterpret_cast<const float4*>(&hs[r][0])[c4];
      acc[r] = fmaf(hv.x, w0, acc[r]);
      acc[r] = fmaf(hv.y, w1, acc[r]);
      acc[r] = fmaf(hv.z, w2, acc[r]);
      acc[r] = fmaf(hv.w, w3, acc[r]);
    }
  }
  const int h = tid >> 5, d = tid & 31;
  #pragma unroll
  for (int r = 0; r < NROW; ++r) {
    const int g = r0 + r;
    const int b = g >> 9, s = g & (S_ - 1);
    out[((b * H_ + h) * S_ + s) * D_ + d] = acc[r];
  }
}

// ---------------------------------------------------------------------------
// Kernel B: scores + mask + softmax + attn@V.
// 1-D grid of 512 blocks, XCD-swizzled: block handles (b, 8 i-rows, 2 heads).
// The 4 head-group blocks sharing an rpe tile get linear ids 8 apart ->
// same XCD (id%8 heuristic), consecutive in that XCD's stream -> rpe tile
// (263 KB) re-served from L2 instead of L3.
// scores[b,h,i,j] = sum_d q[b,h,j,d] * k[b,h,i,d] * rpe[b,i,j,d] / sqrt(D)
// mask: j < station  OR  j == i.  p-row index r = hh*TI + ii.
// ---------------------------------------------------------------------------
__global__ __launch_bounds__(512, 2) void attn_kernel(
    const float* __restrict__ rpe, const float* __restrict__ q_ws,
    const float* __restrict__ k_ws, const float* __restrict__ v_ws,
    const int* __restrict__ station_p, float* __restrict__ o_ws)
{
  __shared__ float k_lds[NR * D_];      // [hh*TI+ii][d]
  __shared__ float p_lds[NR][PSTR];
  __shared__ float sums[NR];
  __shared__ float4 redv[8][NR][8];     // [part][r][d4]

  const int tid = threadIdx.x;
  const int n   = blockIdx.x;                       // 0..511
  const int hg  = (n >> 3) & 3;
  const int t   = (n & 7) | ((n >> 5) << 3);        // 0..127 tile id
  const int b   = t >> 6;
  const int i0  = (t & 63) * TI;
  const int h0  = hg * HC;

  int station = station_p[0];
  if (station > S_) station = S_;
  if (station < 0)  station = 0;

  // stage K: NR rows x 32 d = 512 floats
  {
    const int r = tid >> 5, d = tid & 31;           // r = hh*TI+ii
    const int hh = r >> 3, ii = r & 7;
    k_lds[tid] = k_ws[((b * H_ + h0 + hh) * S_ + i0 + ii) * D_ + d];
  }
  __syncthreads();

  // ---- scores (thread tid == column j; loop over the 8 i-rows) ----
  const int j = tid;
  const bool jlt = (j < station);
  const bool intile = (j >= i0) && (j < i0 + TI);

  float4 q0[8], q1[8];
  if (jlt || intile) {
    const float4* qp0 = reinterpret_cast<const float4*>(
        q_ws + ((b * H_ + h0 + 0) * S_ + j) * D_);
    const float4* qp1 = reinterpret_cast<const float4*>(
        q_ws + ((b * H_ + h0 + 1) * S_ + j) * D_);
    #pragma unroll
    for (int tt = 0; tt < 8; ++tt) { q0[tt] = qp0[tt]; q1[tt] = qp1[tt]; }
  }

  const float4* rbase = reinterpret_cast<const float4*>(
      rpe + (((size_t)b * S_ + i0) * S_ + j) * D_);
  const int rstride = S_ * D_ / 4;   // float4 units between consecutive i

  #pragma unroll
  for (int ii = 0; ii < TI; ++ii) {
    const int i = i0 + ii;
    const bool ok = jlt || (j == i);
    float s0 = -1e30f, s1 = -1e30f;
    if (ok) {
      const float4* rp  = rbase + ii * rstride;
      const float4* kp0 = reinterpret_cast<const float4*>(&k_lds[(0 * TI + ii) * D_]);
      const float4* kp1 = reinterpret_cast<const float4*>(&k_lds[(1 * TI + ii) * D_]);
      float a0 = 0.f, a1 = 0.f;
      #pragma unroll
      for (int tt = 0; tt < 8; ++tt) {
        const float4 rv = rp[tt];
        const float4 k0 = kp0[tt];
        const float4 k1 = kp1[tt];
        a0 = fmaf(q0[tt].x * k0.x, rv.x, a0);
        a0 = fmaf(q0[tt].y * k0.y, rv.y, a0);
        a0 = fmaf(q0[tt].z * k0.z, rv.z, a0);
        a0 = fmaf(q0[tt].w * k0.w, rv.w, a0);
        a1 = fmaf(q1[tt].x * k1.x, rv.x, a1);
        a1 = fmaf(q1[tt].y * k1.y, rv.y, a1);
        a1 = fmaf(q1[tt].z * k1.z, rv.z, a1);
        a1 = fmaf(q1[tt].w * k1.w, rv.w, a1);
      }
      s0 = a0 * 0.17677669529663687f;   // 1/sqrt(32)
      s1 = a1 * 0.17677669529663687f;
    }
    p_lds[0 * TI + ii][j] = s0;
    p_lds[1 * TI + ii][j] = s1;
  }
  __syncthreads();

  // ---- softmax: 16 rows over 8 waves (wave w -> rows w, w+8) ----
  {
    const int w = tid >> 6, lane = tid & 63;
    for (int rr = w; rr < NR; rr += 8) {
      float m = -1e30f;
      #pragma unroll
      for (int jj = lane; jj < S_; jj += 64) m = fmaxf(m, p_lds[rr][jj]);
      #pragma unroll
      for (int o = 32; o; o >>= 1) m = fmaxf(m, __shfl_xor(m, o, 64));
      float sum = 0.f;
      #pragma unroll
      for (int jj = lane; jj < S_; jj += 64) {
        const float p = __expf(p_lds[rr][jj] - m);
        p_lds[rr][jj] = p;
        sum += p;
      }
      #pragma unroll
      for (int o = 32; o; o >>= 1) sum += __shfl_xor(sum, o, 64);
      if (lane == 0) sums[rr] = sum;
    }
  }
  __syncthreads();

  // ---- attn @ V: 8-way jj split (wave = part), lanes = (ii, d4), 2 heads ----
  {
    const int part = tid >> 6;          // 0..7 (wave id)
    const int lane = tid & 63;
    const int ii = lane >> 3, d4 = lane & 7;
    const float4* vp0 = reinterpret_cast<const float4*>(
        v_ws + ((size_t)(b * H_ + h0 + 0) * S_) * D_) + d4;
    const float4* vp1 = reinterpret_cast<const float4*>(
        v_ws + ((size_t)(b * H_ + h0 + 1) * S_) * D_) + d4;
    float4 a0 = {0.f, 0.f, 0.f, 0.f};
    float4 a1 = {0.f, 0.f, 0.f, 0.f};
    #pragma unroll 4
    for (int jj = part; jj < station; jj += 8) {
      const float p0 = p_lds[0 * TI + ii][jj];
      const float p1 = p_lds[1 * TI + ii][jj];
      const float4 v0 = vp0[jj * (D_ / 4)];
      const float4 v1 = vp1[jj * (D_ / 4)];
      a0.x = fmaf(p0, v0.x, a0.x); a0.y = fmaf(p0, v0.y, a0.y);
      a0.z = fmaf(p0, v0.z, a0.z); a0.w = fmaf(p0, v0.w, a0.w);
      a1.x = fmaf(p1, v1.x, a1.x); a1.y = fmaf(p1, v1.y, a1.y);
      a1.z = fmaf(p1, v1.z, a1.z); a1.w = fmaf(p1, v1.w, a1.w);
    }
    const int ig = i0 + ii;
    if (ig >= station && part == (ig & 7)) {
      const float p0 = p_lds[0 * TI + ii][ig];
      const float p1 = p_lds[1 * TI + ii][ig];
      const float4 v0 = vp0[ig * (D_ / 4)];
      const float4 v1 = vp1[ig * (D_ / 4)];
      a0.x = fmaf(p0, v0.x, a0.x); a0.y = fmaf(p0, v0.y, a0.y);
      a0.z = fmaf(p0, v0.z, a0.z); a0.w = fmaf(p0, v0.w, a0.w);
      a1.x = fmaf(p1, v1.x, a1.x); a1.y = fmaf(p1, v1.y, a1.y);
      a1.z = fmaf(p1, v1.z, a1.z); a1.w = fmaf(p1, v1.w, a1.w);
    }
    redv[part][0 * TI + ii][d4] = a0;
    redv[part][1 * TI + ii][d4] = a1;
  }
  __syncthreads();
  if (tid < NR * 8) {
    const int r = tid >> 3, d4 = tid & 7;
    float4 a = redv[0][r][d4];
    #pragma unroll
    for (int p = 1; p < 8; ++p) {
      const float4 x = redv[p][r][d4];
      a.x += x.x; a.y += x.y; a.z += x.z; a.w += x.w;
    }
    const float inv = 1.f / sums[r];
    a.x *= inv; a.y *= inv; a.z *= inv; a.w *= inv;
    const int hh = r >> 3, ii = r & 7;
    reinterpret_cast<float4*>(
        o_ws + ((b * H_ + h0 + hh) * S_ + i0 + ii) * D_)[d4] = a;
  }
}

// ---------------------------------------------------------------------------
// Kernel C: ctx = O @ fc_w + fc_b + hidden, then LayerNorm.
// grid = B*S/NROW, block = 256 (thread per output column m).
// ---------------------------------------------------------------------------
__global__ __launch_bounds__(256) void fc_ln_kernel(
    const float* __restrict__ o_ws, const float* __restrict__ fc_w,
    const float* __restrict__ fc_b, const float* __restrict__ hid,
    const float* __restrict__ ln_w, const float* __restrict__ ln_b,
    float* __restrict__ out)
{
  __shared__ float orow[NROW][HD_];
  __shared__ float red[NROW][4];
  const int tid = threadIdx.x;
  const int r0 = blockIdx.x * NROW;

  for (int idx = tid; idx < NROW * HD_; idx += 256) {
    const int r = idx >> 8, m = idx & 255;
    const int g = r0 + r;
    const int b = g >> 9, i = g & (S_ - 1);
    orow[r][m] = o_ws[((b * H_ + (m >> 5)) * S_ + i) * D_ + (m & 31)];
  }
  __syncthreads();

  float acc[NROW] = {0.f, 0.f, 0.f, 0.f};
  const float* wp = fc_w + tid;
  #pragma unroll 8
  for (int n4 = 0; n4 < HD_ / 4; ++n4) {
    const float w0 = wp[(4 * n4 + 0) * DM_];
    const float w1 = wp[(4 * n4 + 1) * DM_];
    const float w2 = wp[(4 * n4 + 2) * DM_];
    const float w3 = wp[(4 * n4 + 3) * DM_];
    #pragma unroll
    for (int r = 0; r < NROW; ++r) {
      const float4 ov = reinterpret_cast<const float4*>(&orow[r][0])[n4];
      acc[r] = fmaf(ov.x, w0, acc[r]);
      acc[r] = fmaf(ov.y, w1, acc[r]);
      acc[r] = fmaf(ov.z, w2, acc[r]);
      acc[r] = fmaf(ov.w, w3, acc[r]);
    }
  }
  const float bias = fc_b[tid];
  #pragma unroll
  for (int r = 0; r < NROW; ++r) acc[r] += bias + hid[(r0 + r) * DM_ + tid];

  // ---- LayerNorm over DM per row ----
  const int w = tid >> 6, lane = tid & 63;
  float mu[NROW];
  #pragma unroll
  for (int r = 0; r < NROW; ++r) {
    float s = acc[r];
    #pragma unroll
    for (int o = 32; o; o >>= 1) s += __shfl_xor(s, o, 64);
    if (lane == 0) red[r][w] = s;
  }
  __syncthreads();
  #pragma unroll
  for (int r = 0; r < NROW; ++r)
    mu[r] = (red[r][0] + red[r][1] + red[r][2] + red[r][3]) * (1.f / DM_);
  __syncthreads();
  #pragma unroll
  for (int r = 0; r < NROW; ++r) {
    const float dd = acc[r] - mu[r];
    float s = dd * dd;
    #pragma unroll
    for (int o = 32; o; o >>= 1) s += __shfl_xor(s, o, 64);
    if (lane == 0) red[r][w] = s;
  }
  __syncthreads();
  const float lw = ln_w[tid], lb = ln_b[tid];
  #pragma unroll
  for (int r = 0; r < NROW; ++r) {
    const float var = (red[r][0] + red[r][1] + red[r][2] + red[r][3]) * (1.f / DM_);
    out[(r0 + r) * DM_ + tid] =
        (acc[r] - mu[r]) * rsqrtf(var + 1e-6f) * lw + lb;
  }
}

// ---------------------------------------------------------------------------
extern "C" void kernel_launch(void* const* d_in, const int* in_sizes, int n_in,
                              void* d_out, int out_size, void* d_ws, size_t ws_size,
                              hipStream_t stream) {
  const float* hid = (const float*)d_in[0];
  const float* rpe = (const float*)d_in[1];
  const float* wq  = (const float*)d_in[2];
  const float* wk  = (const float*)d_in[3];
  const float* wv  = (const float*)d_in[4];
  const float* fcw = (const float*)d_in[5];
  const float* fcb = (const float*)d_in[6];
  const float* lnw = (const float*)d_in[7];
  const float* lnb = (const float*)d_in[8];
  const int* station = (const int*)d_in[9];
  float* out = (float*)d_out;

  const size_t per = (size_t)B_ * H_ * S_ * D_;   // 262144 floats
  float* q_ws = (float*)d_ws;
  float* k_ws = q_ws + per;
  float* v_ws = k_ws + per;
  float* o_ws = v_ws + per;

  dim3 gA(B_ * S_ / NROW, 3);
  qkv_kernel<<<gA, 256, 0, stream>>>(hid, wq, wk, wv, q_ws, k_ws, v_ws);
  attn_kernel<<<B_ * (S_ / TI) * (H_ / HC), 512, 0, stream>>>(
      rpe, q_ws, k_ws, v_ws, station, o_ws);
  fc_ln_kernel<<<B_ * S_ / NROW, 256, 0, stream>>>(o_ws, fcw, fcb, hid, lnw, lnb, out);
}